// Round 6
// baseline (6710.457 us; speedup 1.0000x reference)
//
#include <hip/hip_runtime.h>
#include <hip/hip_bf16.h>
#include <math.h>

// Problem constants
constexpr int B = 128;
constexpr int T = 256;
constexpr int H = 200;       // hidden
constexpr int G4 = 800;      // 4*H
constexpr int BT = B * T;    // 32768
constexpr int K0 = 360, K0P = 384;   // layer0 input dim, padded to %32
constexpr int K1 = 400, K1P = 416;   // layer1 input dim, padded to %32

typedef __bf16 bf16x8 __attribute__((ext_vector_type(8)));
typedef float f32x4 __attribute__((ext_vector_type(4)));
typedef float f32x2 __attribute__((ext_vector_type(2)));
typedef unsigned short ushortx4 __attribute__((ext_vector_type(4)));

__device__ __forceinline__ float bfr2f(unsigned short u) {
  union { unsigned int i; float f; } x;
  x.i = ((unsigned int)u) << 16;
  return x.f;
}
__device__ __forceinline__ float uif(unsigned u) {
  union { unsigned int i; float f; } x;
  x.i = u;
  return x.f;
}
__device__ __forceinline__ unsigned short f2bu(float f) {
  __hip_bfloat16 b = __float2bfloat16(f);
  return *(unsigned short*)&b;
}
__device__ __forceinline__ float sigm(float x) {
  return 1.0f / (1.0f + __expf(-x));
}
__device__ __forceinline__ float tanh_f(float x) {
  float e = __expf(2.0f * x);
  return (e - 1.0f) / (e + 1.0f);
}

// ---------------------------------------------------------------------------
// Dtype detector (f32 vs bf16 storage of float inputs); see round-2 notes.
__global__ void detect_dtype(const unsigned short* __restrict__ raw,
                             int* __restrict__ flag) {
  __shared__ int cnt[256];
  int c = 0;
  for (int j = 0; j < 32; ++j) {
    unsigned short u = raw[1024 + threadIdx.x * 32 + j];
    int e = (u >> 7) & 0xFF;
    if (e >= 0xC0) ++c;
  }
  cnt[threadIdx.x] = c;
  __syncthreads();
  for (int off = 128; off > 0; off >>= 1) {
    if (threadIdx.x < off) cnt[threadIdx.x] += cnt[threadIdx.x + off];
    __syncthreads();
  }
  if (threadIdx.x == 0) *flag = (cnt[0] > 16) ? 1 : 0;
}

// Generic convert-to-bf16 (f32 world) or raw copy (bf16 world)
__global__ void conv_to_bf16(const void* __restrict__ src,
                             __hip_bfloat16* __restrict__ dst, int n,
                             const int* __restrict__ flag) {
  int f = *flag;
  int stride = gridDim.x * blockDim.x;
  for (int i = blockIdx.x * blockDim.x + threadIdx.x; i < n; i += stride) {
    if (f) dst[i] = __float2bfloat16(((const float*)src)[i]);
    else   ((unsigned short*)dst)[i] = ((const unsigned short*)src)[i];
  }
}

// ---------------------------------------------------------------------------
// Embedding concat into X0 [BT][K0P]
__global__ void embed_kernel(const int* __restrict__ words,
                             const int* __restrict__ pos,
                             const int* __restrict__ ner,
                             const __hip_bfloat16* __restrict__ embC,
                             const __hip_bfloat16* __restrict__ posC,
                             const __hip_bfloat16* __restrict__ nerC,
                             __hip_bfloat16* __restrict__ X0) {
  int bt = blockIdx.x;
  int w = words[bt], p = pos[bt], nr = ner[bt];
  for (int j = threadIdx.x; j < K0P; j += blockDim.x) {
    __hip_bfloat16 v;
    if (j < 300)       v = embC[(size_t)w * 300 + j];
    else if (j < 330)  v = posC[(size_t)p * 30 + (j - 300)];
    else if (j < 360)  v = nerC[(size_t)nr * 30 + (j - 330)];
    else               v = __float2bfloat16(0.0f);
    X0[(size_t)bt * K0P + j] = v;
  }
}

// Zero the K-pad tail columns [400:416) of X1
__global__ void zero_x1_tail(__hip_bfloat16* __restrict__ X1) {
  int idx = blockIdx.x * blockDim.x + threadIdx.x;  // BT*16 threads
  int bt = idx >> 4, j = idx & 15;
  X1[(size_t)bt * K1P + 400 + j] = __float2bfloat16(0.0f);
}

// Pad-copy a weight matrix [rows,K] -> [rows,Kp] with zero fill (+dtype conv)
__global__ void pad_copy(const void* __restrict__ src,
                         __hip_bfloat16* __restrict__ dst, int K, int Kp,
                         const int* __restrict__ flag) {
  int r = blockIdx.x;
  int f = *flag;
  for (int j = threadIdx.x; j < Kp; j += blockDim.x) {
    __hip_bfloat16 v = __float2bfloat16(0.0f);
    if (j < K)
      v = f ? __float2bfloat16(((const float*)src)[(size_t)r * K + j])
            : ((const __hip_bfloat16*)src)[(size_t)r * K + j];
    dst[(size_t)r * Kp + j] = v;
  }
}

// Pack W_hh [800][200] into k-pairwise dwords: Wpack[n][p] = bf16(w[n][2p]) |
// bf16(w[n][2p+1])<<16.
__global__ void pack_whh(const void* __restrict__ src,
                         unsigned* __restrict__ dst,
                         const int* __restrict__ flag) {
  int idx = blockIdx.x * blockDim.x + threadIdx.x;  // 800*100
  if (idx >= G4 * 100) return;
  int f = *flag;
  int n = idx / 100, p = idx % 100;
  unsigned short lo, hi;
  if (f) {
    lo = f2bu(((const float*)src)[(size_t)n * 200 + 2 * p]);
    hi = f2bu(((const float*)src)[(size_t)n * 200 + 2 * p + 1]);
  } else {
    lo = ((const unsigned short*)src)[(size_t)n * 200 + 2 * p];
    hi = ((const unsigned short*)src)[(size_t)n * 200 + 2 * p + 1];
  }
  dst[idx] = (unsigned)lo | ((unsigned)hi << 16);
}

// ---------------------------------------------------------------------------
// MFMA GEMM: C[M,800] = A[M,Kp] @ Bm[800,Kp]^T   (bf16 in, fp32 acc, bf16 out)
__global__ __launch_bounds__(256) void gemm_bt(
    const __hip_bfloat16* __restrict__ A,
    const __hip_bfloat16* __restrict__ Bm,
    __hip_bfloat16* __restrict__ C,
    int N, int Kp) {
  const int lane = threadIdx.x & 63;
  const int wave = threadIdx.x >> 6;
  const int l15 = lane & 15, quad = lane >> 4;
  const int m0 = blockIdx.x * 64 + (wave & 1) * 32;
  const int n0 = blockIdx.y * 64 + (wave >> 1) * 32;

  f32x4 acc[2][2] = {};

  int c0 = n0 + l15;       if (c0 > N - 1) c0 = N - 1;
  int c1 = n0 + 16 + l15;  if (c1 > N - 1) c1 = N - 1;
  const size_t ar0 = (size_t)(m0 + l15) * Kp;
  const size_t ar1 = (size_t)(m0 + 16 + l15) * Kp;
  const size_t br0 = (size_t)c0 * Kp;
  const size_t br1 = (size_t)c1 * Kp;

  for (int k0 = 0; k0 < Kp; k0 += 32) {
    int ko = k0 + quad * 8;
    bf16x8 a0 = *(const bf16x8*)(A + ar0 + ko);
    bf16x8 a1 = *(const bf16x8*)(A + ar1 + ko);
    bf16x8 b0 = *(const bf16x8*)(Bm + br0 + ko);
    bf16x8 b1 = *(const bf16x8*)(Bm + br1 + ko);
    acc[0][0] = __builtin_amdgcn_mfma_f32_16x16x32_bf16(a0, b0, acc[0][0], 0, 0, 0);
    acc[0][1] = __builtin_amdgcn_mfma_f32_16x16x32_bf16(a0, b1, acc[0][1], 0, 0, 0);
    acc[1][0] = __builtin_amdgcn_mfma_f32_16x16x32_bf16(a1, b0, acc[1][0], 0, 0, 0);
    acc[1][1] = __builtin_amdgcn_mfma_f32_16x16x32_bf16(a1, b1, acc[1][1], 0, 0, 0);
  }
  #pragma unroll
  for (int mi = 0; mi < 2; ++mi)
    #pragma unroll
    for (int ni = 0; ni < 2; ++ni)
      #pragma unroll
      for (int r = 0; r < 4; ++r) {
        int row = m0 + mi * 16 + quad * 4 + r;
        int col = n0 + ni * 16 + l15;
        if (col < N)
          C[(size_t)row * N + col] = __float2bfloat16(acc[mi][ni][r]);
      }
}

// ---------------------------------------------------------------------------
// Register-resident-weight LSTM recurrence, 1024-thread version.
// grid 256 = dir*128 + row; block 1024 (16 waves).
// amdgpu_waves_per_eu(4,4) PINS 4 waves/EU (min=max) -> 128-VGPR budget and
// exactly 1 block/CU. Round-5 lesson: __launch_bounds__'s 2nd arg is only a
// MINIMUM — the allocator exceeded it (8 waves/EU, 64 VGPRs) and spilled the
// weight array to scratch (FETCH_SIZE 7.4 GB of spill traffic).
// Thread (kq=tid&3, gslot=tid>>2 in [0,256)): owns k-quarter [kq*50,+50) of
// gates {gslot, 256+gslot, 512+gslot} = 75 packed dwords in registers.
// The 32 tail o-gates (768..799) keep weights in LDS (12.8 KB), processed by
// gslot>=224 (waves 14-15, wave-uniform branch).
// Partials: parts[kq*808 + gate] — 808%32==8 -> within-wave bank aliasing is
// exactly 2-way (free, m136); round-5's stride-5 layout caused 6.5M conflicts.
// 200 reduce threads: sum 4 partials/gate + bias + Gpre, nonlinearity, h->LDS.
__global__ __launch_bounds__(1024)
__attribute__((amdgpu_waves_per_eu(4, 4)))
void lstm_row(
    const __hip_bfloat16* __restrict__ Gpre,   // [2][B*T][800]  x@W_ih^T (no bias)
    const unsigned* __restrict__ Wpack,        // [2][800][100] packed k-pairs
    const __hip_bfloat16* __restrict__ bias_f, // [800]
    const __hip_bfloat16* __restrict__ bias_b, // [800]
    const int* __restrict__ masks,             // [B][T], 1 = pad
    __hip_bfloat16* __restrict__ out,          // [B][T][ostride], cols dir*200..+200
    int ostride,
    float* __restrict__ final_h)               // [B][400] = [hb | hf], or nullptr
{
  const int tid = threadIdx.x;
  const int dir = blockIdx.x >> 7;
  const int row = blockIdx.x & 127;
  const int kq = tid & 3;          // k-quarter
  const int gslot = tid >> 2;      // 0..255
  const bool tail = (gslot >= 224);  // waves 14,15 — wave-uniform

  __shared__ __align__(16) float hsh[200];
  __shared__ float parts[4 * 808];         // [kq][gate(+pad 8)], 12928 B
  __shared__ unsigned wtail[32 * 100];     // gates 768..799, 12800 B

  const unsigned* wb = Wpack + (size_t)dir * G4 * 100;

  // --- LDS copy of tail-gate weights ---
  for (int i = tid; i < 3200; i += 1024) wtail[i] = wb[76800 + i];

  // --- load register weights (one time): 75 dwords/thread ---
  unsigned w0[25], w1[25], w2[25];
  {
    const unsigned* s = wb + (size_t)gslot * 100 + kq * 25;
    #pragma unroll
    for (int p = 0; p < 25; ++p) {
      w0[p] = s[p];
      w1[p] = s[25600 + p];   // gate 256+gslot
      w2[p] = s[51200 + p];   // gate 512+gslot
    }
  }

  // --- reduce-thread constants (u = hidden unit) ---
  const int u = tid;
  const __hip_bfloat16* bias = dir ? bias_b : bias_f;
  float bI = 0.f, bF = 0.f, bG = 0.f, bO = 0.f;
  if (u < 200) {
    bI = __bfloat162float(bias[u]);
    bF = __bfloat162float(bias[200 + u]);
    bG = __bfloat162float(bias[400 + u]);
    bO = __bfloat162float(bias[600 + u]);
  }

  if (tid < 200) hsh[tid] = 0.0f;
  float creg = 0.0f, hreg = 0.0f;
  __syncthreads();

  const unsigned short* gp = (const unsigned short*)Gpre + (size_t)dir * BT * G4;
  const size_t gbase = (size_t)row * T * G4;
  const int* mrow = masks + row * T;

  #pragma unroll 1
  for (int tt = 0; tt < T; ++tt) {
    const int t = dir ? (T - 1 - tt) : tt;
    const size_t goff = gbase + (size_t)t * G4;
    // prefetch gate pre-activations + mask (consumed in the reduce phase)
    unsigned short qI = 0, qF = 0, qG = 0, qO = 0;
    int mk = 0;
    if (u < 200) {
      qI = gp[goff + u];
      qF = gp[goff + 200 + u];
      qG = gp[goff + 400 + u];
      qO = gp[goff + 600 + u];
      mk = mrow[t];
    }

    // --- dot phase: register weights x h (LDS broadcast reads) ---
    const f32x2* hp = (const f32x2*)&hsh[kq * 50];
    f32x2 A0 = {0.f, 0.f}, A1 = {0.f, 0.f}, A2 = {0.f, 0.f};
    #pragma unroll
    for (int p = 0; p < 25; ++p) {
      f32x2 h2 = hp[p];
      unsigned v0 = w0[p], v1 = w1[p], v2 = w2[p];
      f32x2 W0, W1, W2;
      W0[0] = uif(v0 << 16); W0[1] = uif(v0 & 0xffff0000u);
      W1[0] = uif(v1 << 16); W1[1] = uif(v1 & 0xffff0000u);
      W2[0] = uif(v2 << 16); W2[1] = uif(v2 & 0xffff0000u);
      A0 += h2 * W0;
      A1 += h2 * W1;
      A2 += h2 * W2;
    }
    parts[kq * 808 + gslot]       = A0[0] + A0[1];
    parts[kq * 808 + 256 + gslot] = A1[0] + A1[1];
    parts[kq * 808 + 512 + gslot] = A2[0] + A2[1];
    if (tail) {
      const int gt = gslot - 224;  // 0..31
      const unsigned* wt = &wtail[gt * 100 + kq * 25];
      f32x2 A3 = {0.f, 0.f};
      #pragma unroll
      for (int p = 0; p < 25; ++p) {
        unsigned v = wt[p];
        f32x2 W;
        W[0] = uif(v << 16); W[1] = uif(v & 0xffff0000u);
        A3 += hp[p] * W;
      }
      parts[kq * 808 + 768 + gt] = A3[0] + A3[1];
    }
    __syncthreads();

    // --- reduce + nonlinearity (threads 0..199) ---
    if (u < 200) {
      float gi = parts[u]       + parts[808 + u]       + parts[1616 + u]       + parts[2424 + u]       + bI + bfr2f(qI);
      float gf = parts[200 + u] + parts[808 + 200 + u] + parts[1616 + 200 + u] + parts[2424 + 200 + u] + bF + bfr2f(qF);
      float gg = parts[400 + u] + parts[808 + 400 + u] + parts[1616 + 400 + u] + parts[2424 + 400 + u] + bG + bfr2f(qG);
      float go = parts[600 + u] + parts[808 + 600 + u] + parts[1616 + 600 + u] + parts[2424 + 600 + u] + bO + bfr2f(qO);
      float si = sigm(gi), sf = sigm(gf), so = sigm(go);
      float cn = sf * creg + si * tanh_f(gg);
      float hn = so * tanh_f(cn);
      bool kp = (mk == 0);
      creg = kp ? cn : creg;
      hreg = kp ? hn : hreg;
      hsh[u] = hreg;
      out[((size_t)row * T + t) * ostride + dir * H + u] =
          __float2bfloat16(kp ? hn : 0.0f);
    }
    __syncthreads();
  }

  if (final_h != nullptr && u < 200) {
    // glob_h = [hb1 | hf1]: backward dir -> cols 0..199, forward -> 200..399
    int col = dir ? u : (H + u);
    final_h[(size_t)row * 400 + col] = hreg;
  }
}

// ---------------------------------------------------------------------------
// Span sums
__global__ __launch_bounds__(256) void span_sum(
    const __hip_bfloat16* __restrict__ rnn,   // [B][T][400]
    const int* __restrict__ masks,
    const int* __restrict__ subj_pos,
    const int* __restrict__ obj_pos,
    float* __restrict__ obj_h,   // [B][400]
    float* __restrict__ subj_h)  // [B][400]
{
  int b = blockIdx.x;
  for (int d = threadIdx.x; d < 400; d += 256) {
    float ss = 0.f, so = 0.f;
    for (int t = 0; t < T; ++t) {
      int m = masks[b * T + t];
      float v = __bfloat162float(rnn[((size_t)b * T + t) * 400 + d]);
      if (subj_pos[b * T + t] + m == 0) ss += v;
      if (obj_pos[b * T + t] + m == 0) so += v;
    }
    subj_h[(size_t)b * 400 + d] = ss;
    obj_h[(size_t)b * 400 + d] = so;
  }
}

// ---------------------------------------------------------------------------
// Single-query attention pooling. grid = 3*128 (qi = blk>>7, b = blk&127)
__global__ __launch_bounds__(256) void attn_pool_k(
    const float* __restrict__ qbuf,           // [3][B][400]
    const __hip_bfloat16* __restrict__ rnn,   // [B][T][400]
    const int* __restrict__ masks,
    float* __restrict__ outp)                 // [3][B][400]
{
  int b = blockIdx.x & 127;
  int qi = blockIdx.x >> 7;
  __shared__ float qs[400];
  __shared__ float ps[256];
  __shared__ float red[256];
  const float* q = qbuf + ((size_t)qi * B + b) * 400;
  for (int d = threadIdx.x; d < 400; d += 256) qs[d] = q[d];
  __syncthreads();

  int t = threadIdx.x;
  const __hip_bfloat16* kv = rnn + ((size_t)b * T + t) * 400;
  float s = 0.f;
  for (int d = 0; d < 400; ++d) s += qs[d] * __bfloat162float(kv[d]);
  s *= 0.05f;  // 1/sqrt(400)
  if (masks[b * T + t] != 0) s = -1e9f;

  red[t] = s;
  __syncthreads();
  for (int off = 128; off > 0; off >>= 1) {
    if (t < off) red[t] = fmaxf(red[t], red[t + off]);
    __syncthreads();
  }
  float mx = red[0];
  __syncthreads();
  float e = expf(s - mx);
  red[t] = e;
  __syncthreads();
  for (int off = 128; off > 0; off >>= 1) {
    if (t < off) red[t] += red[t + off];
    __syncthreads();
  }
  float inv = 1.0f / red[0];
  ps[t] = e * inv;
  __syncthreads();

  for (int d = threadIdx.x; d < 400; d += 256) {
    float acc = 0.f;
    for (int t2 = 0; t2 < T; ++t2)
      acc += ps[t2] * __bfloat162float(rnn[((size_t)b * T + t2) * 400 + d]);
    outp[((size_t)qi * B + b) * 400 + d] = acc;
  }
}

// ---------------------------------------------------------------------------
// Head
__global__ __launch_bounds__(256) void final_head(
    const float* __restrict__ attn,   // [3][B][400]: 0=obj,1=subj,2=glob
    const __hip_bfloat16* __restrict__ wo_w, const __hip_bfloat16* __restrict__ wo_b,
    const __hip_bfloat16* __restrict__ ws_w, const __hip_bfloat16* __restrict__ ws_b,
    const __hip_bfloat16* __restrict__ wg_w, const __hip_bfloat16* __restrict__ wg_b,
    const __hip_bfloat16* __restrict__ cls_w, const __hip_bfloat16* __restrict__ cls_b,
    void* __restrict__ outp,          // [B][2]
    const int* __restrict__ flag)
{
  int b = blockIdx.x;
  __shared__ float hs[H];
  int j = threadIdx.x;
  if (j < H) {
    float acc = __bfloat162float(wo_b[j]) + __bfloat162float(ws_b[j]) +
                __bfloat162float(wg_b[j]);
    const float* oa = attn + ((size_t)0 * B + b) * 400;
    const float* sa = attn + ((size_t)1 * B + b) * 400;
    const float* ga = attn + ((size_t)2 * B + b) * 400;
    for (int d = 0; d < 400; ++d) {
      acc += oa[d] * __bfloat162float(wo_w[(size_t)j * 400 + d]);
      acc += sa[d] * __bfloat162float(ws_w[(size_t)j * 400 + d]);
      acc += ga[d] * __bfloat162float(wg_w[(size_t)j * 400 + d]);
    }
    hs[j] = fmaxf(acc, 0.0f);
  }
  __syncthreads();
  if (j < 2) {
    float a = __bfloat162float(cls_b[j]);
    for (int k = 0; k < H; ++k)
      a += hs[k] * __bfloat162float(cls_w[(size_t)j * H + k]);
    if (*flag) ((float*)outp)[b * 2 + j] = a;
    else       ((__hip_bfloat16*)outp)[b * 2 + j] = __float2bfloat16(a);
  }
}

// ---------------------------------------------------------------------------
// Workspace layout (bytes)
constexpr size_t O_X0   = 0;            // 32768*384*2  = 25165824
constexpr size_t O_X1   = 25165824;     // 32768*416*2  = 27262976
constexpr size_t O_GPRE = 52428800;     // 2*32768*800*2 = 104857600 (embC overlaid pre-GEMM)
constexpr size_t O_RNN  = 157286400;    // 32768*400*2  = 26214400
constexpr size_t O_WIH0 = 183500800;    // 2*800*384*2  = 1228800
constexpr size_t O_WIH1 = 184729600;    // 2*800*416*2  = 1331200
constexpr size_t O_WPK  = 186060800;    // 4*800*100*4  = 1280000
constexpr size_t O_Q    = 187340800;    // 3*128*400*4  = 614400
constexpr size_t O_ATT  = 187955200;    // 614400
constexpr size_t O_FLAG = 188569600;    // 256
constexpr size_t O_POSC = 188569856;
constexpr size_t O_NERC = 188572864;
constexpr size_t O_BIAS = 188574368;    // 4*800*2 = 6400
constexpr size_t O_WOW  = 188580768;    // 80000*2 = 160000
constexpr size_t O_WSW  = 188740768;
constexpr size_t O_WGW  = 188900768;
constexpr size_t O_WOB  = 189060768;
constexpr size_t O_WSB  = 189061168;
constexpr size_t O_WGB  = 189061568;
constexpr size_t O_CLSW = 189061968;
constexpr size_t O_CLSB = 189062768;

extern "C" void kernel_launch(void* const* d_in, const int* in_sizes, int n_in,
                              void* d_out, int out_size, void* d_ws, size_t ws_size,
                              hipStream_t stream) {
  (void)in_sizes; (void)n_in; (void)out_size; (void)ws_size;

  const int* words = (const int*)d_in[0];
  const int* masks = (const int*)d_in[1];
  const int* pos   = (const int*)d_in[2];
  const int* ner   = (const int*)d_in[3];
  const int* subj  = (const int*)d_in[4];
  const int* obj   = (const int*)d_in[5];
  const void* emb_w = d_in[6];
  const void* pos_w = d_in[7];
  const void* ner_w = d_in[8];
  const void* wih[4]  = {d_in[9],  d_in[12], d_in[15], d_in[18]};
  const void* whh[4]  = {d_in[10], d_in[13], d_in[16], d_in[19]};
  const void* bias[4] = {d_in[11], d_in[14], d_in[17], d_in[20]};
  const void* wo_w = d_in[21]; const void* wo_b = d_in[22];
  const void* ws_w = d_in[23]; const void* ws_b = d_in[24];
  const void* wg_w = d_in[25]; const void* wg_b = d_in[26];
  const void* cls_w = d_in[27]; const void* cls_b = d_in[28];

  char* ws = (char*)d_ws;
  __hip_bfloat16* X0   = (__hip_bfloat16*)(ws + O_X0);
  __hip_bfloat16* X1   = (__hip_bfloat16*)(ws + O_X1);
  __hip_bfloat16* Gpre = (__hip_bfloat16*)(ws + O_GPRE);
  __hip_bfloat16* embC = (__hip_bfloat16*)(ws + O_GPRE);  // overlaid (dead before GEMM)
  __hip_bfloat16* RNN  = (__hip_bfloat16*)(ws + O_RNN);
  __hip_bfloat16* wih0p = (__hip_bfloat16*)(ws + O_WIH0);  // [2][800][384]
  __hip_bfloat16* wih1p = (__hip_bfloat16*)(ws + O_WIH1);  // [2][800][416]
  unsigned* Wpack = (unsigned*)(ws + O_WPK);               // [4][800][100]
  float* qbuf = (float*)(ws + O_Q);    // [3][B][400]: obj, subj, glob
  float* attb = (float*)(ws + O_ATT);  // [3][B][400]
  int* flag = (int*)(ws + O_FLAG);
  __hip_bfloat16* posC = (__hip_bfloat16*)(ws + O_POSC);
  __hip_bfloat16* nerC = (__hip_bfloat16*)(ws + O_NERC);
  __hip_bfloat16* biasC = (__hip_bfloat16*)(ws + O_BIAS);  // [4][800]
  __hip_bfloat16* woW = (__hip_bfloat16*)(ws + O_WOW);
  __hip_bfloat16* wsW = (__hip_bfloat16*)(ws + O_WSW);
  __hip_bfloat16* wgW = (__hip_bfloat16*)(ws + O_WGW);
  __hip_bfloat16* woB = (__hip_bfloat16*)(ws + O_WOB);
  __hip_bfloat16* wsB = (__hip_bfloat16*)(ws + O_WSB);
  __hip_bfloat16* wgB = (__hip_bfloat16*)(ws + O_WGB);
  __hip_bfloat16* clsW = (__hip_bfloat16*)(ws + O_CLSW);
  __hip_bfloat16* clsB = (__hip_bfloat16*)(ws + O_CLSB);

  // --- dtype detect + conversions ---
  detect_dtype<<<1, 256, 0, stream>>>((const unsigned short*)emb_w, flag);
  conv_to_bf16<<<1024, 256, 0, stream>>>(emb_w, embC, 40000 * 300, flag);
  conv_to_bf16<<<2, 256, 0, stream>>>(pos_w, posC, 50 * 30, flag);
  conv_to_bf16<<<1, 256, 0, stream>>>(ner_w, nerC, 25 * 30, flag);
  for (int i = 0; i < 4; ++i)
    conv_to_bf16<<<2, 256, 0, stream>>>(bias[i], biasC + i * G4, G4, flag);
  conv_to_bf16<<<64, 256, 0, stream>>>(wo_w, woW, H * 400, flag);
  conv_to_bf16<<<64, 256, 0, stream>>>(ws_w, wsW, H * 400, flag);
  conv_to_bf16<<<64, 256, 0, stream>>>(wg_w, wgW, H * 400, flag);
  conv_to_bf16<<<1, 256, 0, stream>>>(wo_b, woB, H, flag);
  conv_to_bf16<<<1, 256, 0, stream>>>(ws_b, wsB, H, flag);
  conv_to_bf16<<<1, 256, 0, stream>>>(wg_b, wgB, H, flag);
  conv_to_bf16<<<1, 256, 0, stream>>>(cls_w, clsW, 2 * H, flag);
  conv_to_bf16<<<1, 256, 0, stream>>>(cls_b, clsB, 2, flag);

  // --- weight prep ---
  pad_copy<<<G4, 128, 0, stream>>>(wih[0], wih0p,               K0, K0P, flag);
  pad_copy<<<G4, 128, 0, stream>>>(wih[1], wih0p + G4 * K0P,    K0, K0P, flag);
  pad_copy<<<G4, 128, 0, stream>>>(wih[2], wih1p,               K1, K1P, flag);
  pad_copy<<<G4, 128, 0, stream>>>(wih[3], wih1p + G4 * K1P,    K1, K1P, flag);
  for (int i = 0; i < 4; ++i)
    pack_whh<<<313, 256, 0, stream>>>(whh[i], Wpack + (size_t)i * G4 * 100, flag);

  // --- embedding + X1 pad ---
  embed_kernel<<<BT, 128, 0, stream>>>(words, pos, ner, embC, posC, nerC, X0);
  zero_x1_tail<<<2048, 256, 0, stream>>>(X1);

  dim3 ggrid(BT / 64, 13);

  // --- layer 0: input projections + recurrence ---
  gemm_bt<<<ggrid, 256, 0, stream>>>(X0, wih0p,            Gpre,                   G4, K0P);
  gemm_bt<<<ggrid, 256, 0, stream>>>(X0, wih0p + G4 * K0P, Gpre + (size_t)BT * G4, G4, K0P);
  lstm_row<<<256, 1024, 0, stream>>>(Gpre, Wpack, biasC, biasC + G4, masks,
                                     X1, K1P, nullptr);

  // --- layer 1 ---
  gemm_bt<<<ggrid, 256, 0, stream>>>(X1, wih1p,            Gpre,                   G4, K1P);
  gemm_bt<<<ggrid, 256, 0, stream>>>(X1, wih1p + G4 * K1P, Gpre + (size_t)BT * G4, G4, K1P);
  float* qglob = qbuf + (size_t)2 * B * 400;
  lstm_row<<<256, 1024, 0, stream>>>(Gpre, Wpack + (size_t)2 * G4 * 100,
                                     biasC + 2 * G4, biasC + 3 * G4, masks,
                                     RNN, 400, qglob);

  // --- span sums (obj -> slot0, subj -> slot1) ---
  span_sum<<<B, 256, 0, stream>>>(RNN, masks, subj, obj,
                                  qbuf, qbuf + (size_t)B * 400);

  // --- attention pooling (3 queries) ---
  attn_pool_k<<<3 * B, 256, 0, stream>>>(qbuf, RNN, masks, attb);

  // --- head ---
  final_head<<<B, 256, 0, stream>>>(attb, woW, woB, wsW, wsB, wgW, wgB,
                                    clsW, clsB, d_out, flag);
}

// Round 7
// 2988.111 us; speedup vs baseline: 2.2457x; 2.2457x over previous
//
#include <hip/hip_runtime.h>
#include <hip/hip_bf16.h>
#include <math.h>

// Problem constants
constexpr int B = 128;
constexpr int T = 256;
constexpr int H = 200;       // hidden
constexpr int G4 = 800;      // 4*H
constexpr int BT = B * T;    // 32768
constexpr int K0 = 360, K0P = 384;   // layer0 input dim, padded to %32
constexpr int K1 = 400, K1P = 416;   // layer1 input dim, padded to %32

typedef __bf16 bf16x8 __attribute__((ext_vector_type(8)));
typedef float f32x4 __attribute__((ext_vector_type(4)));
typedef float f32x2 __attribute__((ext_vector_type(2)));
typedef unsigned short ushortx4 __attribute__((ext_vector_type(4)));

__device__ __forceinline__ float bfr2f(unsigned short u) {
  union { unsigned int i; float f; } x;
  x.i = ((unsigned int)u) << 16;
  return x.f;
}
__device__ __forceinline__ float uif(unsigned u) {
  union { unsigned int i; float f; } x;
  x.i = u;
  return x.f;
}
__device__ __forceinline__ f32x2 up2(unsigned u) {
  f32x2 r;
  r[0] = uif(u << 16);
  r[1] = uif(u & 0xffff0000u);
  return r;
}
__device__ __forceinline__ unsigned short f2bu(float f) {
  __hip_bfloat16 b = __float2bfloat16(f);
  return *(unsigned short*)&b;
}
__device__ __forceinline__ float sigm(float x) {
  return 1.0f / (1.0f + __expf(-x));
}
__device__ __forceinline__ float tanh_f(float x) {
  float e = __expf(2.0f * x);
  return (e - 1.0f) / (e + 1.0f);
}

// ---------------------------------------------------------------------------
// Dtype detector (f32 vs bf16 storage of float inputs); see round-2 notes.
__global__ void detect_dtype(const unsigned short* __restrict__ raw,
                             int* __restrict__ flag) {
  __shared__ int cnt[256];
  int c = 0;
  for (int j = 0; j < 32; ++j) {
    unsigned short u = raw[1024 + threadIdx.x * 32 + j];
    int e = (u >> 7) & 0xFF;
    if (e >= 0xC0) ++c;
  }
  cnt[threadIdx.x] = c;
  __syncthreads();
  for (int off = 128; off > 0; off >>= 1) {
    if (threadIdx.x < off) cnt[threadIdx.x] += cnt[threadIdx.x + off];
    __syncthreads();
  }
  if (threadIdx.x == 0) *flag = (cnt[0] > 16) ? 1 : 0;
}

// Generic convert-to-bf16 (f32 world) or raw copy (bf16 world)
__global__ void conv_to_bf16(const void* __restrict__ src,
                             __hip_bfloat16* __restrict__ dst, int n,
                             const int* __restrict__ flag) {
  int f = *flag;
  int stride = gridDim.x * blockDim.x;
  for (int i = blockIdx.x * blockDim.x + threadIdx.x; i < n; i += stride) {
    if (f) dst[i] = __float2bfloat16(((const float*)src)[i]);
    else   ((unsigned short*)dst)[i] = ((const unsigned short*)src)[i];
  }
}

// ---------------------------------------------------------------------------
// Embedding concat into X0 [BT][K0P]
__global__ void embed_kernel(const int* __restrict__ words,
                             const int* __restrict__ pos,
                             const int* __restrict__ ner,
                             const __hip_bfloat16* __restrict__ embC,
                             const __hip_bfloat16* __restrict__ posC,
                             const __hip_bfloat16* __restrict__ nerC,
                             __hip_bfloat16* __restrict__ X0) {
  int bt = blockIdx.x;
  int w = words[bt], p = pos[bt], nr = ner[bt];
  for (int j = threadIdx.x; j < K0P; j += blockDim.x) {
    __hip_bfloat16 v;
    if (j < 300)       v = embC[(size_t)w * 300 + j];
    else if (j < 330)  v = posC[(size_t)p * 30 + (j - 300)];
    else if (j < 360)  v = nerC[(size_t)nr * 30 + (j - 330)];
    else               v = __float2bfloat16(0.0f);
    X0[(size_t)bt * K0P + j] = v;
  }
}

// Zero the K-pad tail columns [400:416) of X1
__global__ void zero_x1_tail(__hip_bfloat16* __restrict__ X1) {
  int idx = blockIdx.x * blockDim.x + threadIdx.x;  // BT*16 threads
  int bt = idx >> 4, j = idx & 15;
  X1[(size_t)bt * K1P + 400 + j] = __float2bfloat16(0.0f);
}

// Pad-copy a weight matrix [rows,K] -> [rows,Kp] with zero fill (+dtype conv)
__global__ void pad_copy(const void* __restrict__ src,
                         __hip_bfloat16* __restrict__ dst, int K, int Kp,
                         const int* __restrict__ flag) {
  int r = blockIdx.x;
  int f = *flag;
  for (int j = threadIdx.x; j < Kp; j += blockDim.x) {
    __hip_bfloat16 v = __float2bfloat16(0.0f);
    if (j < K)
      v = f ? __float2bfloat16(((const float*)src)[(size_t)r * K + j])
            : ((const __hip_bfloat16*)src)[(size_t)r * K + j];
    dst[(size_t)r * Kp + j] = v;
  }
}

// Pack W_hh [800][200] into k-pairwise dwords: Wpack[n][p] = bf16(w[n][2p]) |
// bf16(w[n][2p+1])<<16.
__global__ void pack_whh(const void* __restrict__ src,
                         unsigned* __restrict__ dst,
                         const int* __restrict__ flag) {
  int idx = blockIdx.x * blockDim.x + threadIdx.x;  // 800*100
  if (idx >= G4 * 100) return;
  int f = *flag;
  int n = idx / 100, p = idx % 100;
  unsigned short lo, hi;
  if (f) {
    lo = f2bu(((const float*)src)[(size_t)n * 200 + 2 * p]);
    hi = f2bu(((const float*)src)[(size_t)n * 200 + 2 * p + 1]);
  } else {
    lo = ((const unsigned short*)src)[(size_t)n * 200 + 2 * p];
    hi = ((const unsigned short*)src)[(size_t)n * 200 + 2 * p + 1];
  }
  dst[idx] = (unsigned)lo | ((unsigned)hi << 16);
}

// ---------------------------------------------------------------------------
// MFMA GEMM: C[M,800] = A[M,Kp] @ Bm[800,Kp]^T   (bf16 in, fp32 acc, bf16 out)
__global__ __launch_bounds__(256) void gemm_bt(
    const __hip_bfloat16* __restrict__ A,
    const __hip_bfloat16* __restrict__ Bm,
    __hip_bfloat16* __restrict__ C,
    int N, int Kp) {
  const int lane = threadIdx.x & 63;
  const int wave = threadIdx.x >> 6;
  const int l15 = lane & 15, quad = lane >> 4;
  const int m0 = blockIdx.x * 64 + (wave & 1) * 32;
  const int n0 = blockIdx.y * 64 + (wave >> 1) * 32;

  f32x4 acc[2][2] = {};

  int c0 = n0 + l15;       if (c0 > N - 1) c0 = N - 1;
  int c1 = n0 + 16 + l15;  if (c1 > N - 1) c1 = N - 1;
  const size_t ar0 = (size_t)(m0 + l15) * Kp;
  const size_t ar1 = (size_t)(m0 + 16 + l15) * Kp;
  const size_t br0 = (size_t)c0 * Kp;
  const size_t br1 = (size_t)c1 * Kp;

  for (int k0 = 0; k0 < Kp; k0 += 32) {
    int ko = k0 + quad * 8;
    bf16x8 a0 = *(const bf16x8*)(A + ar0 + ko);
    bf16x8 a1 = *(const bf16x8*)(A + ar1 + ko);
    bf16x8 b0 = *(const bf16x8*)(Bm + br0 + ko);
    bf16x8 b1 = *(const bf16x8*)(Bm + br1 + ko);
    acc[0][0] = __builtin_amdgcn_mfma_f32_16x16x32_bf16(a0, b0, acc[0][0], 0, 0, 0);
    acc[0][1] = __builtin_amdgcn_mfma_f32_16x16x32_bf16(a0, b1, acc[0][1], 0, 0, 0);
    acc[1][0] = __builtin_amdgcn_mfma_f32_16x16x32_bf16(a1, b0, acc[1][0], 0, 0, 0);
    acc[1][1] = __builtin_amdgcn_mfma_f32_16x16x32_bf16(a1, b1, acc[1][1], 0, 0, 0);
  }
  #pragma unroll
  for (int mi = 0; mi < 2; ++mi)
    #pragma unroll
    for (int ni = 0; ni < 2; ++ni)
      #pragma unroll
      for (int r = 0; r < 4; ++r) {
        int row = m0 + mi * 16 + quad * 4 + r;
        int col = n0 + ni * 16 + l15;
        if (col < N)
          C[(size_t)row * N + col] = __float2bfloat16(acc[mi][ni][r]);
      }
}

// ---------------------------------------------------------------------------
// LSTM recurrence: 256-thread blocks, 1 block/CU forced by 124 KB LDS.
// __launch_bounds__(256,1) -> verified 256-VGPR grant (round 3); the big LDS
// caps occupancy at 1 wave/SIMD anyway, so the allocator has no incentive to
// shrink the budget (rounds 3-6 lesson: the occupancy heuristic overrides
// both launch_bounds minimums and amdgpu_waves_per_eu).
// grid 256 = dir*128 + row. Thread (kh=tid&1, gs=tid>>1 in [0,128)):
//   registers: k-half kh of gates {gs+128j, j<4}  = 4*50 = 200 dwords
//   LDS (wlds): gates 512..799 (288 rows, stride 101 -> conflict-free);
//     thread handles {512+gs, 640+gs} (+ 768+gs for wave 0, gs<32).
// Partials parts[kh*804+g]; 200 reduce threads sum 2 halves + bias + Gpre.
__global__ __launch_bounds__(256, 1) void lstm_row(
    const __hip_bfloat16* __restrict__ Gpre,   // [2][B*T][800]  x@W_ih^T (no bias)
    const unsigned* __restrict__ Wpack,        // [2][800][100] packed k-pairs
    const __hip_bfloat16* __restrict__ bias_f, // [800]
    const __hip_bfloat16* __restrict__ bias_b, // [800]
    const int* __restrict__ masks,             // [B][T], 1 = pad
    __hip_bfloat16* __restrict__ out,          // [B][T][ostride], cols dir*200..+200
    int ostride,
    float* __restrict__ final_h)               // [B][400] = [hb | hf], or nullptr
{
  const int tid = threadIdx.x;
  const int dir = blockIdx.x >> 7;
  const int row = blockIdx.x & 127;
  const int kh = tid & 1;          // k-half: k in [kh*100, kh*100+100)
  const int gs = tid >> 1;         // 0..127

  __shared__ __align__(16) float hsh[200];
  __shared__ float parts[2 * 804];           // [kh][gate(+4 pad)], 6432 B
  __shared__ unsigned wlds[288 * 101];       // gates 512..799, 116352 B

  const unsigned* wb = Wpack + (size_t)dir * G4 * 100;

  // --- LDS weights: gates 512..799, row stride 101 ---
  for (int idx = tid; idx < 28800; idx += 256) {
    int g = idx / 100, p = idx - g * 100;
    wlds[g * 101 + p] = wb[(512 + g) * 100 + p];
  }

  // --- register weights: 200 dwords/thread (all indices compile-time) ---
  unsigned w0[50], w1[50], w2[50], w3[50];
  {
    const unsigned* s = wb + (size_t)gs * 100 + kh * 50;
    #pragma unroll
    for (int p = 0; p < 50; ++p) {
      w0[p] = s[p];
      w1[p] = s[12800 + p];   // gate 128+gs
      w2[p] = s[25600 + p];   // gate 256+gs
      w3[p] = s[38400 + p];   // gate 384+gs
    }
  }

  const unsigned* l0 = &wlds[gs * 101 + kh * 50];          // gate 512+gs
  const unsigned* l1 = &wlds[(128 + gs) * 101 + kh * 50];  // gate 640+gs
  const unsigned* l2 = &wlds[(256 + gs) * 101 + kh * 50];  // gate 768+gs (gs<32)

  // --- reduce-thread constants (u = hidden unit) ---
  const int u = tid;
  const __hip_bfloat16* bias = dir ? bias_b : bias_f;
  float bI = 0.f, bF = 0.f, bG = 0.f, bO = 0.f;
  if (u < 200) {
    bI = __bfloat162float(bias[u]);
    bF = __bfloat162float(bias[200 + u]);
    bG = __bfloat162float(bias[400 + u]);
    bO = __bfloat162float(bias[600 + u]);
  }

  if (tid < 200) hsh[tid] = 0.0f;
  float creg = 0.0f, hreg = 0.0f;
  __syncthreads();

  const unsigned short* gp = (const unsigned short*)Gpre + (size_t)dir * BT * G4;
  const size_t gbase = (size_t)row * T * G4;
  const int* mrow = masks + row * T;
  const f32x4* h4 = (const f32x4*)hsh + kh * 25;

  #pragma unroll 1
  for (int tt = 0; tt < T; ++tt) {
    const int t = dir ? (T - 1 - tt) : tt;
    const size_t goff = gbase + (size_t)t * G4;
    // prefetch gate pre-activations + mask (consumed in the reduce phase)
    unsigned short qI = 0, qF = 0, qG = 0, qO = 0;
    int mk = 0;
    if (u < 200) {
      qI = gp[goff + u];
      qF = gp[goff + 200 + u];
      qG = gp[goff + 400 + u];
      qO = gp[goff + 600 + u];
      mk = mrow[t];
    }

    // --- dot phase ---
    f32x2 a0 = {0.f, 0.f}, a1 = {0.f, 0.f}, a2 = {0.f, 0.f}, a3 = {0.f, 0.f};
    f32x2 a4 = {0.f, 0.f}, a5 = {0.f, 0.f};
    #pragma unroll
    for (int pp = 0; pp < 25; ++pp) {
      f32x4 h = h4[pp];
      f32x2 hA; hA[0] = h[0]; hA[1] = h[1];
      f32x2 hB; hB[0] = h[2]; hB[1] = h[3];
      a0 += hA * up2(w0[2 * pp]);  a0 += hB * up2(w0[2 * pp + 1]);
      a1 += hA * up2(w1[2 * pp]);  a1 += hB * up2(w1[2 * pp + 1]);
      a2 += hA * up2(w2[2 * pp]);  a2 += hB * up2(w2[2 * pp + 1]);
      a3 += hA * up2(w3[2 * pp]);  a3 += hB * up2(w3[2 * pp + 1]);
      a4 += hA * up2(l0[2 * pp]);  a4 += hB * up2(l0[2 * pp + 1]);
      a5 += hA * up2(l1[2 * pp]);  a5 += hB * up2(l1[2 * pp + 1]);
    }
    parts[kh * 804 + gs]        = a0[0] + a0[1];
    parts[kh * 804 + 128 + gs]  = a1[0] + a1[1];
    parts[kh * 804 + 256 + gs]  = a2[0] + a2[1];
    parts[kh * 804 + 384 + gs]  = a3[0] + a3[1];
    parts[kh * 804 + 512 + gs]  = a4[0] + a4[1];
    parts[kh * 804 + 640 + gs]  = a5[0] + a5[1];
    if (gs < 32) {               // wave 0 only — wave-uniform tail gate
      f32x2 a6 = {0.f, 0.f};
      #pragma unroll
      for (int pp = 0; pp < 25; ++pp) {
        f32x4 h = h4[pp];
        f32x2 hA; hA[0] = h[0]; hA[1] = h[1];
        f32x2 hB; hB[0] = h[2]; hB[1] = h[3];
        a6 += hA * up2(l2[2 * pp]);  a6 += hB * up2(l2[2 * pp + 1]);
      }
      parts[kh * 804 + 768 + gs] = a6[0] + a6[1];
    }
    __syncthreads();

    // --- reduce + nonlinearity (threads 0..199) ---
    if (u < 200) {
      float gi = parts[u]       + parts[804 + u]        + bI + bfr2f(qI);
      float gf = parts[200 + u] + parts[804 + 200 + u]  + bF + bfr2f(qF);
      float gg = parts[400 + u] + parts[804 + 400 + u]  + bG + bfr2f(qG);
      float go = parts[600 + u] + parts[804 + 600 + u]  + bO + bfr2f(qO);
      float si = sigm(gi), sf = sigm(gf), so = sigm(go);
      float cn = sf * creg + si * tanh_f(gg);
      float hn = so * tanh_f(cn);
      bool kp = (mk == 0);
      creg = kp ? cn : creg;
      hreg = kp ? hn : hreg;
      hsh[u] = hreg;
      out[((size_t)row * T + t) * ostride + dir * H + u] =
          __float2bfloat16(kp ? hn : 0.0f);
    }
    __syncthreads();
  }

  if (final_h != nullptr && u < 200) {
    // glob_h = [hb1 | hf1]: backward dir -> cols 0..199, forward -> 200..399
    int col = dir ? u : (H + u);
    final_h[(size_t)row * 400 + col] = hreg;
  }
}

// ---------------------------------------------------------------------------
// Span sums
__global__ __launch_bounds__(256) void span_sum(
    const __hip_bfloat16* __restrict__ rnn,   // [B][T][400]
    const int* __restrict__ masks,
    const int* __restrict__ subj_pos,
    const int* __restrict__ obj_pos,
    float* __restrict__ obj_h,   // [B][400]
    float* __restrict__ subj_h)  // [B][400]
{
  int b = blockIdx.x;
  for (int d = threadIdx.x; d < 400; d += 256) {
    float ss = 0.f, so = 0.f;
    for (int t = 0; t < T; ++t) {
      int m = masks[b * T + t];
      float v = __bfloat162float(rnn[((size_t)b * T + t) * 400 + d]);
      if (subj_pos[b * T + t] + m == 0) ss += v;
      if (obj_pos[b * T + t] + m == 0) so += v;
    }
    subj_h[(size_t)b * 400 + d] = ss;
    obj_h[(size_t)b * 400 + d] = so;
  }
}

// ---------------------------------------------------------------------------
// Single-query attention pooling. grid = 3*128 (qi = blk>>7, b = blk&127)
__global__ __launch_bounds__(256) void attn_pool_k(
    const float* __restrict__ qbuf,           // [3][B][400]
    const __hip_bfloat16* __restrict__ rnn,   // [B][T][400]
    const int* __restrict__ masks,
    float* __restrict__ outp)                 // [3][B][400]
{
  int b = blockIdx.x & 127;
  int qi = blockIdx.x >> 7;
  __shared__ float qs[400];
  __shared__ float ps[256];
  __shared__ float red[256];
  const float* q = qbuf + ((size_t)qi * B + b) * 400;
  for (int d = threadIdx.x; d < 400; d += 256) qs[d] = q[d];
  __syncthreads();

  int t = threadIdx.x;
  const __hip_bfloat16* kv = rnn + ((size_t)b * T + t) * 400;
  float s = 0.f;
  for (int d = 0; d < 400; ++d) s += qs[d] * __bfloat162float(kv[d]);
  s *= 0.05f;  // 1/sqrt(400)
  if (masks[b * T + t] != 0) s = -1e9f;

  red[t] = s;
  __syncthreads();
  for (int off = 128; off > 0; off >>= 1) {
    if (t < off) red[t] = fmaxf(red[t], red[t + off]);
    __syncthreads();
  }
  float mx = red[0];
  __syncthreads();
  float e = expf(s - mx);
  red[t] = e;
  __syncthreads();
  for (int off = 128; off > 0; off >>= 1) {
    if (t < off) red[t] += red[t + off];
    __syncthreads();
  }
  float inv = 1.0f / red[0];
  ps[t] = e * inv;
  __syncthreads();

  for (int d = threadIdx.x; d < 400; d += 256) {
    float acc = 0.f;
    for (int t2 = 0; t2 < T; ++t2)
      acc += ps[t2] * __bfloat162float(rnn[((size_t)b * T + t2) * 400 + d]);
    outp[((size_t)qi * B + b) * 400 + d] = acc;
  }
}

// ---------------------------------------------------------------------------
// Head
__global__ __launch_bounds__(256) void final_head(
    const float* __restrict__ attn,   // [3][B][400]: 0=obj,1=subj,2=glob
    const __hip_bfloat16* __restrict__ wo_w, const __hip_bfloat16* __restrict__ wo_b,
    const __hip_bfloat16* __restrict__ ws_w, const __hip_bfloat16* __restrict__ ws_b,
    const __hip_bfloat16* __restrict__ wg_w, const __hip_bfloat16* __restrict__ wg_b,
    const __hip_bfloat16* __restrict__ cls_w, const __hip_bfloat16* __restrict__ cls_b,
    void* __restrict__ outp,          // [B][2]
    const int* __restrict__ flag)
{
  int b = blockIdx.x;
  __shared__ float hs[H];
  int j = threadIdx.x;
  if (j < H) {
    float acc = __bfloat162float(wo_b[j]) + __bfloat162float(ws_b[j]) +
                __bfloat162float(wg_b[j]);
    const float* oa = attn + ((size_t)0 * B + b) * 400;
    const float* sa = attn + ((size_t)1 * B + b) * 400;
    const float* ga = attn + ((size_t)2 * B + b) * 400;
    for (int d = 0; d < 400; ++d) {
      acc += oa[d] * __bfloat162float(wo_w[(size_t)j * 400 + d]);
      acc += sa[d] * __bfloat162float(ws_w[(size_t)j * 400 + d]);
      acc += ga[d] * __bfloat162float(wg_w[(size_t)j * 400 + d]);
    }
    hs[j] = fmaxf(acc, 0.0f);
  }
  __syncthreads();
  if (j < 2) {
    float a = __bfloat162float(cls_b[j]);
    for (int k = 0; k < H; ++k)
      a += hs[k] * __bfloat162float(cls_w[(size_t)j * H + k]);
    if (*flag) ((float*)outp)[b * 2 + j] = a;
    else       ((__hip_bfloat16*)outp)[b * 2 + j] = __float2bfloat16(a);
  }
}

// ---------------------------------------------------------------------------
// Workspace layout (bytes)
constexpr size_t O_X0   = 0;            // 32768*384*2  = 25165824
constexpr size_t O_X1   = 25165824;     // 32768*416*2  = 27262976
constexpr size_t O_GPRE = 52428800;     // 2*32768*800*2 = 104857600 (embC overlaid pre-GEMM)
constexpr size_t O_RNN  = 157286400;    // 32768*400*2  = 26214400
constexpr size_t O_WIH0 = 183500800;    // 2*800*384*2  = 1228800
constexpr size_t O_WIH1 = 184729600;    // 2*800*416*2  = 1331200
constexpr size_t O_WPK  = 186060800;    // 4*800*100*4  = 1280000
constexpr size_t O_Q    = 187340800;    // 3*128*400*4  = 614400
constexpr size_t O_ATT  = 187955200;    // 614400
constexpr size_t O_FLAG = 188569600;    // 256
constexpr size_t O_POSC = 188569856;
constexpr size_t O_NERC = 188572864;
constexpr size_t O_BIAS = 188574368;    // 4*800*2 = 6400
constexpr size_t O_WOW  = 188580768;    // 80000*2 = 160000
constexpr size_t O_WSW  = 188740768;
constexpr size_t O_WGW  = 188900768;
constexpr size_t O_WOB  = 189060768;
constexpr size_t O_WSB  = 189061168;
constexpr size_t O_WGB  = 189061568;
constexpr size_t O_CLSW = 189061968;
constexpr size_t O_CLSB = 189062768;

extern "C" void kernel_launch(void* const* d_in, const int* in_sizes, int n_in,
                              void* d_out, int out_size, void* d_ws, size_t ws_size,
                              hipStream_t stream) {
  (void)in_sizes; (void)n_in; (void)out_size; (void)ws_size;

  const int* words = (const int*)d_in[0];
  const int* masks = (const int*)d_in[1];
  const int* pos   = (const int*)d_in[2];
  const int* ner   = (const int*)d_in[3];
  const int* subj  = (const int*)d_in[4];
  const int* obj   = (const int*)d_in[5];
  const void* emb_w = d_in[6];
  const void* pos_w = d_in[7];
  const void* ner_w = d_in[8];
  const void* wih[4]  = {d_in[9],  d_in[12], d_in[15], d_in[18]};
  const void* whh[4]  = {d_in[10], d_in[13], d_in[16], d_in[19]};
  const void* bias[4] = {d_in[11], d_in[14], d_in[17], d_in[20]};
  const void* wo_w = d_in[21]; const void* wo_b = d_in[22];
  const void* ws_w = d_in[23]; const void* ws_b = d_in[24];
  const void* wg_w = d_in[25]; const void* wg_b = d_in[26];
  const void* cls_w = d_in[27]; const void* cls_b = d_in[28];

  char* ws = (char*)d_ws;
  __hip_bfloat16* X0   = (__hip_bfloat16*)(ws + O_X0);
  __hip_bfloat16* X1   = (__hip_bfloat16*)(ws + O_X1);
  __hip_bfloat16* Gpre = (__hip_bfloat16*)(ws + O_GPRE);
  __hip_bfloat16* embC = (__hip_bfloat16*)(ws + O_GPRE);  // overlaid (dead before GEMM)
  __hip_bfloat16* RNN  = (__hip_bfloat16*)(ws + O_RNN);
  __hip_bfloat16* wih0p = (__hip_bfloat16*)(ws + O_WIH0);  // [2][800][384]
  __hip_bfloat16* wih1p = (__hip_bfloat16*)(ws + O_WIH1);  // [2][800][416]
  unsigned* Wpack = (unsigned*)(ws + O_WPK);               // [4][800][100]
  float* qbuf = (float*)(ws + O_Q);    // [3][B][400]: obj, subj, glob
  float* attb = (float*)(ws + O_ATT);  // [3][B][400]
  int* flag = (int*)(ws + O_FLAG);
  __hip_bfloat16* posC = (__hip_bfloat16*)(ws + O_POSC);
  __hip_bfloat16* nerC = (__hip_bfloat16*)(ws + O_NERC);
  __hip_bfloat16* biasC = (__hip_bfloat16*)(ws + O_BIAS);  // [4][800]
  __hip_bfloat16* woW = (__hip_bfloat16*)(ws + O_WOW);
  __hip_bfloat16* wsW = (__hip_bfloat16*)(ws + O_WSW);
  __hip_bfloat16* wgW = (__hip_bfloat16*)(ws + O_WGW);
  __hip_bfloat16* woB = (__hip_bfloat16*)(ws + O_WOB);
  __hip_bfloat16* wsB = (__hip_bfloat16*)(ws + O_WSB);
  __hip_bfloat16* wgB = (__hip_bfloat16*)(ws + O_WGB);
  __hip_bfloat16* clsW = (__hip_bfloat16*)(ws + O_CLSW);
  __hip_bfloat16* clsB = (__hip_bfloat16*)(ws + O_CLSB);

  // --- dtype detect + conversions ---
  detect_dtype<<<1, 256, 0, stream>>>((const unsigned short*)emb_w, flag);
  conv_to_bf16<<<1024, 256, 0, stream>>>(emb_w, embC, 40000 * 300, flag);
  conv_to_bf16<<<2, 256, 0, stream>>>(pos_w, posC, 50 * 30, flag);
  conv_to_bf16<<<1, 256, 0, stream>>>(ner_w, nerC, 25 * 30, flag);
  for (int i = 0; i < 4; ++i)
    conv_to_bf16<<<2, 256, 0, stream>>>(bias[i], biasC + i * G4, G4, flag);
  conv_to_bf16<<<64, 256, 0, stream>>>(wo_w, woW, H * 400, flag);
  conv_to_bf16<<<64, 256, 0, stream>>>(ws_w, wsW, H * 400, flag);
  conv_to_bf16<<<64, 256, 0, stream>>>(wg_w, wgW, H * 400, flag);
  conv_to_bf16<<<1, 256, 0, stream>>>(wo_b, woB, H, flag);
  conv_to_bf16<<<1, 256, 0, stream>>>(ws_b, wsB, H, flag);
  conv_to_bf16<<<1, 256, 0, stream>>>(wg_b, wgB, H, flag);
  conv_to_bf16<<<1, 256, 0, stream>>>(cls_w, clsW, 2 * H, flag);
  conv_to_bf16<<<1, 256, 0, stream>>>(cls_b, clsB, 2, flag);

  // --- weight prep ---
  pad_copy<<<G4, 128, 0, stream>>>(wih[0], wih0p,               K0, K0P, flag);
  pad_copy<<<G4, 128, 0, stream>>>(wih[1], wih0p + G4 * K0P,    K0, K0P, flag);
  pad_copy<<<G4, 128, 0, stream>>>(wih[2], wih1p,               K1, K1P, flag);
  pad_copy<<<G4, 128, 0, stream>>>(wih[3], wih1p + G4 * K1P,    K1, K1P, flag);
  for (int i = 0; i < 4; ++i)
    pack_whh<<<313, 256, 0, stream>>>(whh[i], Wpack + (size_t)i * G4 * 100, flag);

  // --- embedding + X1 pad ---
  embed_kernel<<<BT, 128, 0, stream>>>(words, pos, ner, embC, posC, nerC, X0);
  zero_x1_tail<<<2048, 256, 0, stream>>>(X1);

  dim3 ggrid(BT / 64, 13);

  // --- layer 0: input projections + recurrence ---
  gemm_bt<<<ggrid, 256, 0, stream>>>(X0, wih0p,            Gpre,                   G4, K0P);
  gemm_bt<<<ggrid, 256, 0, stream>>>(X0, wih0p + G4 * K0P, Gpre + (size_t)BT * G4, G4, K0P);
  lstm_row<<<256, 256, 0, stream>>>(Gpre, Wpack, biasC, biasC + G4, masks,
                                    X1, K1P, nullptr);

  // --- layer 1 ---
  gemm_bt<<<ggrid, 256, 0, stream>>>(X1, wih1p,            Gpre,                   G4, K1P);
  gemm_bt<<<ggrid, 256, 0, stream>>>(X1, wih1p + G4 * K1P, Gpre + (size_t)BT * G4, G4, K1P);
  float* qglob = qbuf + (size_t)2 * B * 400;
  lstm_row<<<256, 256, 0, stream>>>(Gpre, Wpack + (size_t)2 * G4 * 100,
                                    biasC + 2 * G4, biasC + 3 * G4, masks,
                                    RNN, 400, qglob);

  // --- span sums (obj -> slot0, subj -> slot1) ---
  span_sum<<<B, 256, 0, stream>>>(RNN, masks, subj, obj,
                                  qbuf, qbuf + (size_t)B * 400);

  // --- attention pooling (3 queries) ---
  attn_pool_k<<<3 * B, 256, 0, stream>>>(qbuf, RNN, masks, attb);

  // --- head ---
  final_head<<<B, 256, 0, stream>>>(attb, woW, woB, wsW, wsB, wgW, wgB,
                                    clsW, clsB, d_out, flag);
}